// Round 9
// baseline (195.076 us; speedup 1.0000x reference)
//
#include <hip/hip_runtime.h>

#define CNT    2048
#define TPB    256
#define RPB    4            // waves per block; one row per wave
#define NCHUNK 8            // chunks per row
#define CSTEP  256          // steps per chunk
#define GFL    768          // gyro floats per chunk
#define BUFF   1024         // floats per chunk buffer (768 gyro + 256 ts)
#define WBUF   (3*BUFF+12)  // depth-3 ring + 12-float pad (lane63 Tb overread)

struct Q { float w, x, y, z; };

__device__ __forceinline__ Q qmul(const Q a, const Q b) {
    Q o;
    o.w = fmaf(a.w, b.w, fmaf(-a.x, b.x, fmaf(-a.y, b.y, -a.z * b.z)));
    o.x = fmaf(a.w, b.x, fmaf( a.x, b.w, fmaf( a.y, b.z, -a.z * b.y)));
    o.y = fmaf(a.w, b.y, fmaf(-a.x, b.z, fmaf( a.y, b.w,  a.z * b.x)));
    o.z = fmaf(a.w, b.z, fmaf( a.x, b.y, fmaf(-a.y, b.x,  a.z * b.w)));
    return o;
}

__device__ __forceinline__ Q qmul1(const Q a, const float bx, const float by, const float bz) {
    Q o;
    o.w = fmaf(-a.x, bx, fmaf(-a.y, by, fmaf(-a.z, bz, a.w)));
    o.x = fmaf( a.w, bx, fmaf( a.y, bz, fmaf(-a.z, by, a.x)));
    o.y = fmaf( a.w, by, fmaf(-a.x, bz, fmaf( a.z, bx, a.y)));
    o.z = fmaf( a.w, bz, fmaf( a.x, by, fmaf(-a.y, bx, a.z)));
    return o;
}

__device__ __forceinline__ float prelu(const float x, const float a, const float one_m_a) {
    return fmaf(one_m_a, fmaxf(x, 0.0f), a * x);
}

// async global->LDS DMA, 16B/lane; LDS dest = wave-uniform base (HW adds lane*16)
__device__ __forceinline__ void dma16(const float* g, float* l) {
    __builtin_amdgcn_global_load_lds(
        (const __attribute__((address_space(1))) void*)g,
        (__attribute__((address_space(3))) void*)l,
        16, 0, 0);
}

// counted wait: allow n DMAs to REMAIN in flight (never 0 in the steady loop)
#define WAITV(n) do { asm volatile("s_waitcnt vmcnt(" #n ")" ::: "memory"); \
                      __builtin_amdgcn_sched_barrier(0); } while (0)

__global__ __launch_bounds__(TPB, 3) void quat_scan_kernel(
    const float* __restrict__ ts,    // (B, CNT)
    const float* __restrict__ gyro,  // (B, CNT, 3)
    const float* __restrict__ sq,    // (B, 4)
    const float* __restrict__ W1, const float* __restrict__ b1, const float* __restrict__ a1p,
    const float* __restrict__ W2, const float* __restrict__ b2, const float* __restrict__ a2p,
    float* __restrict__ out,         // (B, 4)
    const int B)
{
    __shared__ float lds[RPB][WBUF];     // 49,344 B -> 3 blocks/CU, 12 waves/CU

    const int lane = threadIdx.x & 63;
    const int wid  = threadIdx.x >> 6;
    const int row  = blockIdx.x * RPB + wid;
    if (row >= B) return;                // wave-uniform (never taken at B=4096)

    float w1[9], w2[9], bb1[3], bb2[3];
    #pragma unroll
    for (int i = 0; i < 9; ++i) { w1[i] = W1[i]; w2[i] = W2[i]; }
    #pragma unroll
    for (int i = 0; i < 3; ++i) { bb1[i] = b1[i]; bb2[i] = b2[i]; }
    const float a1 = a1p[0], a2 = a2p[0];
    const float oma1 = 1.0f - a1, oma2 = 1.0f - a2;

    auto gfv = [&](const float vx, const float vy, const float vz,
                   float& gx, float& gy, float& gz) {
        float h0 = fmaf(w1[0], vx, fmaf(w1[1], vy, fmaf(w1[2], vz, bb1[0])));
        float h1 = fmaf(w1[3], vx, fmaf(w1[4], vy, fmaf(w1[5], vz, bb1[1])));
        float h2 = fmaf(w1[6], vx, fmaf(w1[7], vy, fmaf(w1[8], vz, bb1[2])));
        h0 = prelu(h0, a1, oma1);
        h1 = prelu(h1, a1, oma1);
        h2 = prelu(h2, a1, oma1);
        float u0 = fmaf(w2[0], h0, fmaf(w2[1], h1, fmaf(w2[2], h2, bb2[0])));
        float u1 = fmaf(w2[3], h0, fmaf(w2[4], h1, fmaf(w2[5], h2, bb2[1])));
        float u2 = fmaf(w2[6], h0, fmaf(w2[7], h1, fmaf(w2[8], h2, bb2[2])));
        gx = prelu(u0, a2, oma2) + vx;
        gy = prelu(u1, a2, oma2) + vy;
        gz = prelu(u2, a2, oma2) + vz;
    };

    const float* grow = gyro + (size_t)row * (CNT * 3);
    const float* trow = ts   + (size_t)row * CNT;
    float* bufs = &lds[wid][0];

    // DMA one chunk into ring slot k: 3x 1KB gyro + 1x 1KB ts, fully coalesced
    auto issue = [&](const int c, const int k) {
        const float* gs = grow + c * GFL + lane * 4;
        float* bp = bufs + k * BUFF;
        dma16(gs +   0, bp +   0);
        dma16(gs + 256, bp + 256);
        dma16(gs + 512, bp + 512);
        dma16(trow + c * CSTEP + lane * 4, bp + GFL);
    };

    issue(0, 0); issue(1, 1); issue(2, 2);   // 12 in flight
    Q acc = {1.0f, 0.0f, 0.0f, 0.0f};
    WAITV(8);                                 // chunk 0 landed (1,2 in flight)

// one chunk iteration. WVACT: counted wait making chunk c+1 visible; PREF:
// issue of chunk c+3 into the slot this iteration just finished reading.
// In-flight trace (4 DMAs/chunk): enter iter c with {c+1,c+2}; WAITV(4)
// leaves {c+2} -> chunk c+1 landed; bottom issue -> {c+2,c+3}. c=6: {7} ->
// WAITV(0); c=7: queue empty, boundary is the dt=0 pad.
#define ITER(c, WVACT, PREF)                                                  \
{                                                                             \
    const float4* gb = (const float4*)(bufs + ((c) % 3) * BUFF);              \
    const float4* tb = (const float4*)(bufs + ((c) % 3) * BUFF + GFL);        \
    const float4 Wa = gb[3 * lane + 0];                                       \
    const float4 Wb = gb[3 * lane + 1];                                       \
    const float4 Wc_ = gb[3 * lane + 2];                                      \
    const float4 Wd = gb[3 * lane + 3];                                       \
    const float4 Ta = tb[lane];                                               \
    const float4 Tb = tb[lane + 1];                                           \
    Q q = {1.0f, 0.0f, 0.0f, 0.0f};                                           \
    float ax, ay, az, bx, by, bz;                                             \
    gfv(Wa.x, Wa.y, Wa.z, ax, ay, az);                                        \
    gfv(Wa.w, Wb.x, Wb.y, bx, by, bz);                                        \
    { const float s = 0.25f * (Ta.y - Ta.x);                                  \
      q = qmul1(q, (ax + bx) * s, (ay + by) * s, (az + bz) * s); }            \
    ax = bx; ay = by; az = bz;                                                \
    gfv(Wb.z, Wb.w, Wc_.x, bx, by, bz);                                       \
    { const float s = 0.25f * (Ta.z - Ta.y);                                  \
      q = qmul1(q, (ax + bx) * s, (ay + by) * s, (az + bz) * s); }            \
    ax = bx; ay = by; az = bz;                                                \
    gfv(Wc_.y, Wc_.z, Wc_.w, bx, by, bz);                                     \
    { const float s = 0.25f * (Ta.w - Ta.z);                                  \
      q = qmul1(q, (ax + bx) * s, (ay + by) * s, (az + bz) * s); }            \
    ax = bx; ay = by; az = bz;                                                \
    WVACT;                                                                    \
    float rx = Wd.x, ry = Wd.y, rz = Wd.z, t4 = Tb.x;                         \
    if ((c) < NCHUNK - 1) {                                                   \
        const float* nb = bufs + (((c) + 1) % 3) * BUFF;                      \
        const float4 Xg = ((const float4*)nb)[0];  /* uniform -> broadcast */ \
        const float  Xt = nb[GFL];                                            \
        if (lane == 63) { rx = Xg.x; ry = Xg.y; rz = Xg.z; t4 = Xt; }         \
    } else {                                                                  \
        if (lane == 63) t4 = Ta.w;       /* global step 2047: dt = 0 pad */   \
    }                                                                         \
    gfv(rx, ry, rz, bx, by, bz);                                              \
    { const float s = 0.25f * (t4 - Ta.w);                                    \
      q = qmul1(q, (ax + bx) * s, (ay + by) * s, (az + bz) * s); }            \
    { const float n2  = fmaf(q.w, q.w, fmaf(q.x, q.x, fmaf(q.y, q.y, q.z * q.z))); \
      const float inv = 1.0f / sqrtf(n2);                                     \
      q.w *= inv; q.x *= inv; q.y *= inv; q.z *= inv; }                       \
    _Pragma("unroll")                                                         \
    for (int sft = 1; sft < 64; sft <<= 1) {                                  \
        Q o;                                                                  \
        o.w = __shfl_down(q.w, sft);                                          \
        o.x = __shfl_down(q.x, sft);                                          \
        o.y = __shfl_down(q.y, sft);                                          \
        o.z = __shfl_down(q.z, sft);                                          \
        q = qmul(q, o);                                                       \
    }                                                                         \
    acc = qmul(acc, q);                                                       \
    PREF;                                                                     \
}

    ITER(0, WAITV(4), issue(3, 0))
    ITER(1, WAITV(4), issue(4, 1))
    ITER(2, WAITV(4), issue(5, 2))
    ITER(3, WAITV(4), issue(6, 0))
    ITER(4, WAITV(4), issue(7, 1))
    ITER(5, WAITV(4), )
    ITER(6, WAITV(0), )
    ITER(7,         , )

#undef ITER

    if (lane == 0) {
        const float4 s0 = ((const float4*)(sq + (size_t)row * 4))[0];
        const Q q0 = {s0.x, s0.y, s0.z, s0.w};
        Q qf = qmul(q0, acc);
        const float n   = sqrtf(fmaf(qf.w, qf.w, fmaf(qf.x, qf.x, fmaf(qf.y, qf.y, qf.z * qf.z))));
        const float inv = 1.0f / fmaxf(n, 1e-12f);
        float4 o;
        o.x = qf.w * inv; o.y = qf.x * inv; o.z = qf.y * inv; o.w = qf.z * inv;
        ((float4*)(out + (size_t)row * 4))[0] = o;
    }
}

extern "C" void kernel_launch(void* const* d_in, const int* in_sizes, int n_in,
                              void* d_out, int out_size, void* d_ws, size_t ws_size,
                              hipStream_t stream) {
    const float* ts   = (const float*)d_in[0];  // timestampns_set (B, CNT)
    const float* gyro = (const float*)d_in[1];  // gyro_set (B, CNT, 3)
    const float* sq   = (const float*)d_in[2];  // start_quat (B, 4)
    const float* W1   = (const float*)d_in[3];
    const float* b1   = (const float*)d_in[4];
    const float* a1   = (const float*)d_in[5];
    const float* W2   = (const float*)d_in[6];
    const float* b2   = (const float*)d_in[7];
    const float* a2   = (const float*)d_in[8];
    float* out = (float*)d_out;

    const int B = in_sizes[0] / CNT;  // 4096
    const int grid = (B + RPB - 1) / RPB;

    quat_scan_kernel<<<grid, TPB, 0, stream>>>(ts, gyro, sq, W1, b1, a1, W2, b2, a2, out, B);
}

// Round 10
// 183.398 us; speedup vs baseline: 1.0637x; 1.0637x over previous
//
#include <hip/hip_runtime.h>

#define CNT   2048
#define TPB   256
#define CH    4          // steps per thread
#define NWAVE (TPB / 64)

struct Q { float w, x, y, z; };

__device__ __forceinline__ Q qmul(const Q a, const Q b) {
    Q o;
    o.w = fmaf(a.w, b.w, fmaf(-a.x, b.x, fmaf(-a.y, b.y, -a.z * b.z)));
    o.x = fmaf(a.w, b.x, fmaf( a.x, b.w, fmaf( a.y, b.z, -a.z * b.y)));
    o.y = fmaf(a.w, b.y, fmaf(-a.x, b.z, fmaf( a.y, b.w,  a.z * b.x)));
    o.z = fmaf(a.w, b.z, fmaf( a.x, b.y, fmaf(-a.y, b.x,  a.z * b.w)));
    return o;
}

__device__ __forceinline__ Q qmul1(const Q a, const float bx, const float by, const float bz) {
    Q o;
    o.w = fmaf(-a.x, bx, fmaf(-a.y, by, fmaf(-a.z, bz, a.w)));
    o.x = fmaf( a.w, bx, fmaf( a.y, bz, fmaf(-a.z, by, a.x)));
    o.y = fmaf( a.w, by, fmaf(-a.x, bz, fmaf( a.z, bx, a.y)));
    o.z = fmaf( a.w, bz, fmaf( a.x, by, fmaf(-a.y, bx, a.z)));
    return o;
}

__device__ __forceinline__ float prelu(const float x, const float a, const float one_m_a) {
    return fmaf(one_m_a, fmaxf(x, 0.0f), a * x);
}

// ---- K1: one HALF-ROW (1024 steps) per 256-thread block; 4 steps/thread.
// 8192 blocks = 32768 waves (32/CU supply); VGPR capped to 64 -> 8 waves/SIMD
// resident. Writes the half-row quaternion product to ws[bid].
__global__ __launch_bounds__(TPB, 8) void half_scan_kernel(
    const float* __restrict__ ts,    // (B, CNT)
    const float* __restrict__ gyro,  // (B, CNT, 3)
    const float* __restrict__ W1, const float* __restrict__ b1, const float* __restrict__ a1p,
    const float* __restrict__ W2, const float* __restrict__ b2, const float* __restrict__ a2p,
    float* __restrict__ ws)          // (2B, 4) half-row products
{
    __shared__ Q s_q[NWAVE];

    const int tid  = threadIdx.x;
    const int bid  = blockIdx.x;
    const int row  = bid >> 1;
    const int S0   = ((bid & 1) << 10) + tid * CH;     // global step 0..2044
    const bool last = (S0 + CH >= CNT);                // only S0 == 2044

    // ---- burst loads first (maximum overlap window): 4 gyro float4 + 2 ts float4
    const float4* gp4 = (const float4*)(gyro + (size_t)row * (CNT * 3));
    const float4* tp4 = (const float4*)(ts   + (size_t)row * CNT);
    const int q0 = (3 * S0) >> 2;                      // 3*S0 divisible by 4
    const float4 Ga = gp4[q0];
    const float4 Gb = gp4[q0 + 1];
    const float4 Gc = gp4[q0 + 2];
    const float4 Gd = gp4[last ? (q0 + 2) : (q0 + 3)]; // clamp: garbage feeds dt=0 pad only
    const int t0 = S0 >> 2;
    const float4 Tv = tp4[t0];
    const float4 Tw = tp4[last ? t0 : (t0 + 1)];

    // ---- params: wave-uniform -> SGPRs
    float w1[9], w2[9], bb1[3], bb2[3];
    #pragma unroll
    for (int i = 0; i < 9; ++i) { w1[i] = W1[i]; w2[i] = W2[i]; }
    #pragma unroll
    for (int i = 0; i < 3; ++i) { bb1[i] = b1[i]; bb2[i] = b2[i]; }
    const float a1 = a1p[0], a2 = a2p[0];
    const float oma1 = 1.0f - a1, oma2 = 1.0f - a2;

    auto gfv = [&](const float vx, const float vy, const float vz,
                   float& gx, float& gy, float& gz) {
        float h0 = fmaf(w1[0], vx, fmaf(w1[1], vy, fmaf(w1[2], vz, bb1[0])));
        float h1 = fmaf(w1[3], vx, fmaf(w1[4], vy, fmaf(w1[5], vz, bb1[1])));
        float h2 = fmaf(w1[6], vx, fmaf(w1[7], vy, fmaf(w1[8], vz, bb1[2])));
        h0 = prelu(h0, a1, oma1);
        h1 = prelu(h1, a1, oma1);
        h2 = prelu(h2, a1, oma1);
        float u0 = fmaf(w2[0], h0, fmaf(w2[1], h1, fmaf(w2[2], h2, bb2[0])));
        float u1 = fmaf(w2[3], h0, fmaf(w2[4], h1, fmaf(w2[5], h2, bb2[1])));
        float u2 = fmaf(w2[6], h0, fmaf(w2[7], h1, fmaf(w2[8], h2, bb2[2])));
        gx = prelu(u0, a2, oma2) + vx;
        gy = prelu(u1, a2, oma2) + vy;
        gz = prelu(u2, a2, oma2) + vz;
    };

    // window floats: samples k=0..4 at gw[3k+c]; gw = {Ga,Gb,Gc,Gd} (const idx only)
    const float gw0  = Ga.x, gw1  = Ga.y, gw2  = Ga.z, gw3  = Ga.w;
    const float gw4  = Gb.x, gw5  = Gb.y, gw6  = Gb.z, gw7  = Gb.w;
    const float gw8  = Gc.x, gw9  = Gc.y, gw10 = Gc.z, gw11 = Gc.w;
    const float gw12 = Gd.x, gw13 = Gd.y, gw14 = Gd.z;
    const float rt0 = Tv.x, rt1 = Tv.y, rt2 = Tv.z, rt3 = Tv.w;
    const float rt4 = last ? Tv.w : Tw.x;              // dt=0 pad for step 2047

    Q q = {1.0f, 0.0f, 0.0f, 0.0f};
    float ax, ay, az, bx, by, bz;
    gfv(gw0, gw1, gw2, ax, ay, az);
    gfv(gw3, gw4, gw5, bx, by, bz);
    { const float s = 0.25f * (rt1 - rt0);
      q = qmul1(q, (ax + bx) * s, (ay + by) * s, (az + bz) * s); }
    ax = bx; ay = by; az = bz;
    gfv(gw6, gw7, gw8, bx, by, bz);
    { const float s = 0.25f * (rt2 - rt1);
      q = qmul1(q, (ax + bx) * s, (ay + by) * s, (az + bz) * s); }
    ax = bx; ay = by; az = bz;
    gfv(gw9, gw10, gw11, bx, by, bz);
    { const float s = 0.25f * (rt3 - rt2);
      q = qmul1(q, (ax + bx) * s, (ay + by) * s, (az + bz) * s); }
    ax = bx; ay = by; az = bz;
    gfv(gw12, gw13, gw14, bx, by, bz);
    { const float s = 0.25f * (rt4 - rt3);
      q = qmul1(q, (ax + bx) * s, (ay + by) * s, (az + bz) * s); }

    // normalize thread product (norm >= 1)
    {
        const float n2  = fmaf(q.w, q.w, fmaf(q.x, q.x, fmaf(q.y, q.y, q.z * q.z)));
        const float inv = 1.0f / sqrtf(n2);
        q.w *= inv; q.x *= inv; q.y *= inv; q.z *= inv;
    }

    // ordered 64-lane butterfly: lane 0 gets P_0 (x) ... (x) P_63
    #pragma unroll
    for (int sft = 1; sft < 64; sft <<= 1) {
        Q o;
        o.w = __shfl_down(q.w, sft);
        o.x = __shfl_down(q.x, sft);
        o.y = __shfl_down(q.y, sft);
        o.z = __shfl_down(q.z, sft);
        q = qmul(q, o);
    }

    const int lane = tid & 63;
    const int wid  = tid >> 6;
    if (lane == 0) s_q[wid] = q;
    __syncthreads();

    if (tid == 0) {
        Q acc = s_q[0];
        #pragma unroll
        for (int w = 1; w < NWAVE; ++w) acc = qmul(acc, s_q[w]);
        const float n2  = fmaf(acc.w, acc.w, fmaf(acc.x, acc.x, fmaf(acc.y, acc.y, acc.z * acc.z)));
        const float inv = 1.0f / sqrtf(n2);
        float4 o;
        o.x = acc.w * inv; o.y = acc.x * inv; o.z = acc.y * inv; o.w = acc.z * inv;
        ((float4*)(ws + (size_t)bid * 4))[0] = o;
    }
}

// ---- K2: combine half-row products, apply start quat, normalize. Trivial.
__global__ __launch_bounds__(TPB) void combine_kernel(
    const float* __restrict__ ws,    // (2B, 4)
    const float* __restrict__ sq,    // (B, 4)
    float* __restrict__ out,         // (B, 4)
    const int B)
{
    const int i = blockIdx.x * TPB + threadIdx.x;
    if (i >= B) return;
    const float4 h0 = ((const float4*)(ws + (size_t)(2 * i)     * 4))[0];
    const float4 h1 = ((const float4*)(ws + (size_t)(2 * i + 1) * 4))[0];
    const Q a = {h0.x, h0.y, h0.z, h0.w};
    const Q b = {h1.x, h1.y, h1.z, h1.w};
    const Q full = qmul(a, b);
    const float4 s0 = ((const float4*)(sq + (size_t)i * 4))[0];
    const Q q0 = {s0.x, s0.y, s0.z, s0.w};
    Q qf = qmul(q0, full);
    const float n   = sqrtf(fmaf(qf.w, qf.w, fmaf(qf.x, qf.x, fmaf(qf.y, qf.y, qf.z * qf.z))));
    const float inv = 1.0f / fmaxf(n, 1e-12f);
    float4 o;
    o.x = qf.w * inv; o.y = qf.x * inv; o.z = qf.y * inv; o.w = qf.z * inv;
    ((float4*)(out + (size_t)i * 4))[0] = o;
}

extern "C" void kernel_launch(void* const* d_in, const int* in_sizes, int n_in,
                              void* d_out, int out_size, void* d_ws, size_t ws_size,
                              hipStream_t stream) {
    const float* ts   = (const float*)d_in[0];  // timestampns_set (B, CNT)
    const float* gyro = (const float*)d_in[1];  // gyro_set (B, CNT, 3)
    const float* sq   = (const float*)d_in[2];  // start_quat (B, 4)
    const float* W1   = (const float*)d_in[3];
    const float* b1   = (const float*)d_in[4];
    const float* a1   = (const float*)d_in[5];
    const float* W2   = (const float*)d_in[6];
    const float* b2   = (const float*)d_in[7];
    const float* a2   = (const float*)d_in[8];
    float* out = (float*)d_out;
    float* ws  = (float*)d_ws;      // needs 2*B*4 floats = 128 KB

    const int B = in_sizes[0] / CNT;  // 4096

    half_scan_kernel<<<2 * B, TPB, 0, stream>>>(ts, gyro, W1, b1, a1, W2, b2, a2, ws);
    combine_kernel<<<(B + TPB - 1) / TPB, TPB, 0, stream>>>(ws, sq, out, B);
}

// Round 11
// 181.884 us; speedup vs baseline: 1.0725x; 1.0083x over previous
//
#include <hip/hip_runtime.h>

#define CNT   2048
#define TPB   512        // one block = one row: 512 threads x 4 steps = 2048
#define CH    4          // steps per thread
#define NWAVE (TPB / 64)

struct Q { float w, x, y, z; };

__device__ __forceinline__ Q qmul(const Q a, const Q b) {
    Q o;
    o.w = fmaf(a.w, b.w, fmaf(-a.x, b.x, fmaf(-a.y, b.y, -a.z * b.z)));
    o.x = fmaf(a.w, b.x, fmaf( a.x, b.w, fmaf( a.y, b.z, -a.z * b.y)));
    o.y = fmaf(a.w, b.y, fmaf(-a.x, b.z, fmaf( a.y, b.w,  a.z * b.x)));
    o.z = fmaf(a.w, b.z, fmaf( a.x, b.y, fmaf(-a.y, b.x,  a.z * b.w)));
    return o;
}

__device__ __forceinline__ Q qmul1(const Q a, const float bx, const float by, const float bz) {
    Q o;
    o.w = fmaf(-a.x, bx, fmaf(-a.y, by, fmaf(-a.z, bz, a.w)));
    o.x = fmaf( a.w, bx, fmaf( a.y, bz, fmaf(-a.z, by, a.x)));
    o.y = fmaf( a.w, by, fmaf(-a.x, bz, fmaf( a.z, bx, a.y)));
    o.z = fmaf( a.w, bz, fmaf( a.x, by, fmaf(-a.y, bx, a.z)));
    return o;
}

__device__ __forceinline__ float prelu(const float x, const float a, const float one_m_a) {
    return fmaf(one_m_a, fmaxf(x, 0.0f), a * x);
}

// one row per block; 8 waves/EU resident (VGPR capped at 64); single launch,
// in-block combine (no workspace, no second kernel).
__global__ __launch_bounds__(TPB, 8) void row_scan_kernel(
    const float* __restrict__ ts,    // (B, CNT)
    const float* __restrict__ gyro,  // (B, CNT, 3)
    const float* __restrict__ sq,    // (B, 4)
    const float* __restrict__ W1, const float* __restrict__ b1, const float* __restrict__ a1p,
    const float* __restrict__ W2, const float* __restrict__ b2, const float* __restrict__ a2p,
    float* __restrict__ out)         // (B, 4)
{
    __shared__ Q s_q[NWAVE];

    const int  tid  = threadIdx.x;
    const int  row  = blockIdx.x;
    const int  S0   = tid * CH;                // steps S0..S0+3 (+pad at row end)
    const bool last = (tid == TPB - 1);

    // ---- burst loads first: 4 gyro float4 + 2 ts float4 (3*S0 = 12*tid, 16B-aligned)
    const float4* gp4 = (const float4*)(gyro + (size_t)row * (CNT * 3));
    const float4* tp4 = (const float4*)(ts   + (size_t)row * CNT);
    const int q0 = 3 * tid;                    // float4 index
    const float4 Ga = gp4[q0];
    const float4 Gb = gp4[q0 + 1];
    const float4 Gc = gp4[q0 + 2];
    const float4 Gd = gp4[last ? (q0 + 2) : (q0 + 3)];  // clamp: feeds dt=0 pad only
    const float4 Tv = tp4[tid];
    const float4 Tw = tp4[last ? tid : (tid + 1)];

    // ---- params: wave-uniform -> SGPRs
    float w1[9], w2[9], bb1[3], bb2[3];
    #pragma unroll
    for (int i = 0; i < 9; ++i) { w1[i] = W1[i]; w2[i] = W2[i]; }
    #pragma unroll
    for (int i = 0; i < 3; ++i) { bb1[i] = b1[i]; bb2[i] = b2[i]; }
    const float a1 = a1p[0], a2 = a2p[0];
    const float oma1 = 1.0f - a1, oma2 = 1.0f - a2;

    auto gfv = [&](const float vx, const float vy, const float vz,
                   float& gx, float& gy, float& gz) {
        float h0 = fmaf(w1[0], vx, fmaf(w1[1], vy, fmaf(w1[2], vz, bb1[0])));
        float h1 = fmaf(w1[3], vx, fmaf(w1[4], vy, fmaf(w1[5], vz, bb1[1])));
        float h2 = fmaf(w1[6], vx, fmaf(w1[7], vy, fmaf(w1[8], vz, bb1[2])));
        h0 = prelu(h0, a1, oma1);
        h1 = prelu(h1, a1, oma1);
        h2 = prelu(h2, a1, oma1);
        float u0 = fmaf(w2[0], h0, fmaf(w2[1], h1, fmaf(w2[2], h2, bb2[0])));
        float u1 = fmaf(w2[3], h0, fmaf(w2[4], h1, fmaf(w2[5], h2, bb2[1])));
        float u2 = fmaf(w2[6], h0, fmaf(w2[7], h1, fmaf(w2[8], h2, bb2[2])));
        gx = prelu(u0, a2, oma2) + vx;
        gy = prelu(u1, a2, oma2) + vy;
        gz = prelu(u2, a2, oma2) + vz;
    };

    // window floats: sample k=0..4 at gw[3k+c] (constant indices only)
    const float gw0  = Ga.x, gw1  = Ga.y, gw2  = Ga.z, gw3  = Ga.w;
    const float gw4  = Gb.x, gw5  = Gb.y, gw6  = Gb.z, gw7  = Gb.w;
    const float gw8  = Gc.x, gw9  = Gc.y, gw10 = Gc.z, gw11 = Gc.w;
    const float gw12 = Gd.x, gw13 = Gd.y, gw14 = Gd.z;
    const float rt0 = Tv.x, rt1 = Tv.y, rt2 = Tv.z, rt3 = Tv.w;
    const float rt4 = last ? Tv.w : Tw.x;      // dt=0 pad for global step 2047

    // ---- batched g-evaluations (independent of q -> full ILP, short critical path)
    float g0x,g0y,g0z, g1x,g1y,g1z, g2x,g2y,g2z, g3x,g3y,g3z, g4x,g4y,g4z;
    gfv(gw0,  gw1,  gw2,  g0x, g0y, g0z);
    gfv(gw3,  gw4,  gw5,  g1x, g1y, g1z);
    gfv(gw6,  gw7,  gw8,  g2x, g2y, g2z);
    gfv(gw9,  gw10, gw11, g3x, g3y, g3z);
    gfv(gw12, gw13, gw14, g4x, g4y, g4z);

    // ---- 4-step ordered product (only the qmul1 chain is serial)
    const float s0 = 0.25f * (rt1 - rt0);
    const float s1 = 0.25f * (rt2 - rt1);
    const float s2 = 0.25f * (rt3 - rt2);
    const float s3 = 0.25f * (rt4 - rt3);
    Q q = {1.0f, 0.0f, 0.0f, 0.0f};
    q = qmul1(q, (g0x + g1x) * s0, (g0y + g1y) * s0, (g0z + g1z) * s0);
    q = qmul1(q, (g1x + g2x) * s1, (g1y + g2y) * s1, (g1z + g2z) * s1);
    q = qmul1(q, (g2x + g3x) * s2, (g2y + g3y) * s2, (g2z + g3z) * s2);
    q = qmul1(q, (g3x + g4x) * s3, (g3y + g4y) * s3, (g3z + g4z) * s3);

    // normalize thread product (norm >= 1)
    {
        const float n2  = fmaf(q.w, q.w, fmaf(q.x, q.x, fmaf(q.y, q.y, q.z * q.z)));
        const float inv = 1.0f / sqrtf(n2);
        q.w *= inv; q.x *= inv; q.y *= inv; q.z *= inv;
    }

    // ---- ordered 64-lane butterfly: lane 0 gets P_0 (x) ... (x) P_63
    #pragma unroll
    for (int sft = 1; sft < 64; sft <<= 1) {
        Q o;
        o.w = __shfl_down(q.w, sft);
        o.x = __shfl_down(q.x, sft);
        o.y = __shfl_down(q.y, sft);
        o.z = __shfl_down(q.z, sft);
        q = qmul(q, o);
    }

    const int lane = tid & 63;
    const int wid  = tid >> 6;
    if (lane == 0) s_q[wid] = q;
    __syncthreads();

    // ---- epilogue: combine 8 wave products in order, apply start quat, store
    if (tid == 0) {
        Q acc = s_q[0];
        #pragma unroll
        for (int w = 1; w < NWAVE; ++w) acc = qmul(acc, s_q[w]);
        const float4 s0q = ((const float4*)(sq + (size_t)row * 4))[0];
        const Q qz = {s0q.x, s0q.y, s0q.z, s0q.w};
        Q qf = qmul(qz, acc);
        const float n   = sqrtf(fmaf(qf.w, qf.w, fmaf(qf.x, qf.x, fmaf(qf.y, qf.y, qf.z * qf.z))));
        const float inv = 1.0f / fmaxf(n, 1e-12f);
        float4 o;
        o.x = qf.w * inv; o.y = qf.x * inv; o.z = qf.y * inv; o.w = qf.z * inv;
        ((float4*)(out + (size_t)row * 4))[0] = o;
    }
}

extern "C" void kernel_launch(void* const* d_in, const int* in_sizes, int n_in,
                              void* d_out, int out_size, void* d_ws, size_t ws_size,
                              hipStream_t stream) {
    const float* ts   = (const float*)d_in[0];  // timestampns_set (B, CNT)
    const float* gyro = (const float*)d_in[1];  // gyro_set (B, CNT, 3)
    const float* sq   = (const float*)d_in[2];  // start_quat (B, 4)
    const float* W1   = (const float*)d_in[3];
    const float* b1   = (const float*)d_in[4];
    const float* a1   = (const float*)d_in[5];
    const float* W2   = (const float*)d_in[6];
    const float* b2   = (const float*)d_in[7];
    const float* a2   = (const float*)d_in[8];
    float* out = (float*)d_out;

    const int B = in_sizes[0] / CNT;  // 4096

    row_scan_kernel<<<B, TPB, 0, stream>>>(ts, gyro, sq, W1, b1, a1, W2, b2, a2, out);
}